// Round 8
// baseline (93.782 us; speedup 1.0000x reference)
//
#include <hip/hip_runtime.h>

typedef __bf16 bf16x8 __attribute__((ext_vector_type(8)));
typedef float  f32x4  __attribute__((ext_vector_type(4)));

__device__ __forceinline__ unsigned short f2bf(float f) {
  unsigned u = __float_as_uint(f);
  u = u + 0x7fffu + ((u >> 16) & 1u);   // RNE
  return (unsigned short)(u >> 16);
}
__device__ __forceinline__ float bf2f(unsigned short h) {
  return __uint_as_float(((unsigned)h) << 16);
}

// K0: convert x (f32) -> xb (bf16), 8 elems/thread
__global__ __launch_bounds__(256) void cvt_bf16(
    const float* __restrict__ x, unsigned short* __restrict__ xb, int total8) {
  int i = blockIdx.x * 256 + threadIdx.x;
  if (i >= total8) return;
  const float4* p = (const float4*)(x + (size_t)i * 8);
  float4 a = p[0], b = p[1];
  union { unsigned short u[8]; uint4 v; } r;
  r.u[0] = f2bf(a.x); r.u[1] = f2bf(a.y); r.u[2] = f2bf(a.z); r.u[3] = f2bf(a.w);
  r.u[4] = f2bf(b.x); r.u[5] = f2bf(b.y); r.u[6] = f2bf(b.z); r.u[7] = f2bf(b.w);
  ((uint4*)xb)[i] = r.v;
}

// K1: mean aggregation. 1 node per wave. Quad-edge gathers: each vmem instr
// fetches 4 edges (lane l: edge-quad member r=l>>4, feature chunk c=l&15,
// 8B uint2 of bf16 / 16B float4). 4x fewer gather requests than row-per-instr.
// Index vector loaded 64-wide once per 48-edge pass; per-quad indices via
// __shfl (ds_bpermute). Epilogue: shfl_xor(16,32) folds the 4 edge groups.
template <bool BF, bool AGGBF>
__global__ __launch_bounds__(256) void agg_k(
    const float* __restrict__ x, const unsigned short* __restrict__ xb,
    const int* __restrict__ row, const int* __restrict__ colptr,
    float* __restrict__ aggf, unsigned short* __restrict__ aggb, int N) {
  int wid  = blockIdx.x * 4 + (threadIdx.x >> 6);
  int lane = threadIdx.x & 63;
  if (wid >= N) return;
  int s = __builtin_amdgcn_readfirstlane(colptr[wid]);
  int e = __builtin_amdgcn_readfirstlane(colptr[wid + 1]);
  int r = lane >> 4;          // edge within quad (0..3)
  int c = lane & 15;          // feature chunk (4 feats each)
  float a0 = 0.f, a1 = 0.f, a2 = 0.f, a3 = 0.f;

  const int DEPTH = BF ? 12 : 8;       // quads in flight
  const int CH    = DEPTH * 4;         // edges per pass

  int t = s;
  while (t < e) {
    int rem  = e - t;
    int nseg = rem < CH ? rem : CH;
    int idxv = row[min(t + lane, e - 1)];   // 64 indices, one trip
    uint2  gb[12];
    float4 gf[8];
    // ---- issue phase: all quad-gathers in flight ----
    #pragma unroll
    for (int q = 0; q < DEPTH; ++q) {
      if (q * 4 < nseg) {
        int pos = min(q * 4 + r, nseg - 1);
        int mi  = __shfl(idxv, pos);
        if (BF) gb[q] = *(const uint2*)(xb + (size_t)mi * 64 + c * 4);
        else    gf[q] = *(const float4*)(x + (size_t)mi * 64 + c * 4);
      }
    }
    // ---- consume phase ----
    #pragma unroll
    for (int q = 0; q < DEPTH; ++q) {
      if (q * 4 < nseg) {
        float f0, f1, f2, f3;
        if (BF) {
          unsigned ux = gb[q].x, uy = gb[q].y;
          f0 = __uint_as_float(ux << 16);
          f1 = __uint_as_float(ux & 0xffff0000u);
          f2 = __uint_as_float(uy << 16);
          f3 = __uint_as_float(uy & 0xffff0000u);
        } else {
          f0 = gf[q].x; f1 = gf[q].y; f2 = gf[q].z; f3 = gf[q].w;
        }
        if (q * 4 + r < nseg) {   // exec-predicated adds
          a0 += f0; a1 += f1; a2 += f2; a3 += f3;
        }
      }
    }
    t += CH;
  }

  // fold the 4 edge groups (lanes c, c+16, c+32, c+48)
  a0 += __shfl_xor(a0, 16); a0 += __shfl_xor(a0, 32);
  a1 += __shfl_xor(a1, 16); a1 += __shfl_xor(a1, 32);
  a2 += __shfl_xor(a2, 16); a2 += __shfl_xor(a2, 32);
  a3 += __shfl_xor(a3, 16); a3 += __shfl_xor(a3, 32);

  int deg = e - s;
  float scale = (deg > 0) ? (1.0f / (float)deg) : 0.0f;
  a0 *= scale; a1 *= scale; a2 *= scale; a3 *= scale;

  if (r == 0) {   // 16 lanes write the 64-feat row
    if (AGGBF) {
      uint2 p;
      p.x = (unsigned)f2bf(a0) | ((unsigned)f2bf(a1) << 16);
      p.y = (unsigned)f2bf(a2) | ((unsigned)f2bf(a3) << 16);
      *(uint2*)(aggb + (size_t)wid * 64 + c * 4) = p;
    } else {
      float4 p; p.x = a0; p.y = a1; p.z = a2; p.w = a3;
      *(float4*)(aggf + (size_t)wid * 64 + c * 4) = p;
    }
  }
}

// K2: out[n] = b + [agg|x] @ W^T via bf16 MFMA 16x16x32.
// AGGBF: agg half comes from bf16 ws buffer; else f32 in-place from out.
template <bool BF, bool AGGBF>
__global__ __launch_bounds__(256) void sage_mm(
    const float* __restrict__ x, const unsigned short* __restrict__ xb,
    const unsigned short* __restrict__ aggb,
    const float* __restrict__ W, const float* __restrict__ b,
    float* __restrict__ out, int N) {
  __shared__ unsigned short ft[128][136];
  int tid = threadIdx.x;
  int l = tid & 63, w = tid >> 6;
  int colr = l & 15, kg = l >> 4;
  int n0 = blockIdx.x * 128;
  int rows = N - n0; if (rows > 128) rows = 128;

  bf16x8 bfrag[4][4];
  float bias[4];
  #pragma unroll
  for (int c = 0; c < 4; ++c) {
    bias[c] = b[c * 16 + colr];
    #pragma unroll
    for (int kq = 0; kq < 4; ++kq) {
      const float* wp = W + (size_t)(c * 16 + colr) * 128 + kq * 32 + kg * 8;
      float4 wa = *(const float4*)wp;
      float4 wb = *(const float4*)(wp + 4);
      union { unsigned short u[8]; bf16x8 v; } r;
      r.u[0] = f2bf(wa.x); r.u[1] = f2bf(wa.y); r.u[2] = f2bf(wa.z); r.u[3] = f2bf(wa.w);
      r.u[4] = f2bf(wb.x); r.u[5] = f2bf(wb.y); r.u[6] = f2bf(wb.z); r.u[7] = f2bf(wb.w);
      bfrag[c][kq] = r.v;
    }
  }

  const float* aggsrcf = out + (size_t)n0 * 64;
  #pragma unroll
  for (int it = 0; it < 4; ++it) {
    int flat = it * 2048 + tid * 8;
    int n = flat >> 6, k = flat & 63;
    { // agg half -> ft[n][0..63]
      uint4 v = make_uint4(0, 0, 0, 0);
      if (n < rows) {
        if (AGGBF) {
          v = *(const uint4*)(aggb + ((size_t)(n0 + n) * 64 + k));
        } else {
          const float4* p = (const float4*)(aggsrcf + (size_t)n * 64 + k);
          float4 a = p[0], bb = p[1];
          union { unsigned short u[8]; uint4 vv; } r;
          r.u[0] = f2bf(a.x);  r.u[1] = f2bf(a.y);  r.u[2] = f2bf(a.z);  r.u[3] = f2bf(a.w);
          r.u[4] = f2bf(bb.x); r.u[5] = f2bf(bb.y); r.u[6] = f2bf(bb.z); r.u[7] = f2bf(bb.w);
          v = r.vv;
        }
      }
      *(uint4*)&ft[n][k] = v;
    }
    { // x half -> ft[n][64..127]
      uint4 v = make_uint4(0, 0, 0, 0);
      if (n < rows) {
        if (BF) {
          v = *(const uint4*)(xb + ((size_t)(n0 + n) * 64 + k));
        } else {
          const float4* p = (const float4*)(x + (size_t)(n0 + n) * 64 + k);
          float4 a = p[0], bb = p[1];
          union { unsigned short u[8]; uint4 vv; } r;
          r.u[0] = f2bf(a.x);  r.u[1] = f2bf(a.y);  r.u[2] = f2bf(a.z);  r.u[3] = f2bf(a.w);
          r.u[4] = f2bf(bb.x); r.u[5] = f2bf(bb.y); r.u[6] = f2bf(bb.z); r.u[7] = f2bf(bb.w);
          v = r.vv;
        }
      }
      *(uint4*)&ft[n][64 + k] = v;
    }
  }
  __syncthreads();

  f32x4 acc[2][4];
  #pragma unroll
  for (int c = 0; c < 4; ++c) {
    acc[0][c] = (f32x4){bias[c], bias[c], bias[c], bias[c]};
    acc[1][c] = acc[0][c];
  }

  #pragma unroll
  for (int kq = 0; kq < 4; ++kq) {
    bf16x8 a0 = *(const bf16x8*)&ft[w * 32 + colr][kq * 32 + kg * 8];
    bf16x8 a1 = *(const bf16x8*)&ft[w * 32 + 16 + colr][kq * 32 + kg * 8];
    #pragma unroll
    for (int c = 0; c < 4; ++c) {
      acc[0][c] = __builtin_amdgcn_mfma_f32_16x16x32_bf16(a0, bfrag[c][kq], acc[0][c], 0, 0, 0);
      acc[1][c] = __builtin_amdgcn_mfma_f32_16x16x32_bf16(a1, bfrag[c][kq], acc[1][c], 0, 0, 0);
    }
  }

  #pragma unroll
  for (int m = 0; m < 2; ++m) {
    int nodeb = n0 + w * 32 + m * 16 + kg * 4;
    #pragma unroll
    for (int c = 0; c < 4; ++c) {
      #pragma unroll
      for (int r = 0; r < 4; ++r) {
        int node = nodeb + r;
        if (node < N) out[(size_t)node * 64 + c * 16 + colr] = acc[m][c][r];
      }
    }
  }
}

extern "C" void kernel_launch(void* const* d_in, const int* in_sizes, int n_in,
                              void* d_out, int out_size, void* d_ws, size_t ws_size,
                              hipStream_t stream) {
  const float* x      = (const float*)d_in[0];
  const int*   row    = (const int*)d_in[1];
  const int*   colptr = (const int*)d_in[2];
  const float* W      = (const float*)d_in[3];
  const float* b      = (const float*)d_in[4];
  float* out = (float*)d_out;

  int N = in_sizes[0] / 64;
  size_t nb_bf = (size_t)N * 64 * 2;   // bf16 x copy
  unsigned short* xb = (unsigned short*)d_ws;
  unsigned short* xa = (unsigned short*)((char*)d_ws + nb_bf);  // bf16 agg

  int total8 = N * 8;
  int nbc = (total8 + 255) / 256;
  int nba = (N + 3) / 4;
  int nbm = (N + 127) / 128;

  if (ws_size >= 2 * nb_bf) {
    cvt_bf16<<<nbc, 256, 0, stream>>>(x, xb, total8);
    agg_k<true, true><<<nba, 256, 0, stream>>>(x, xb, row, colptr, out, xa, N);
    sage_mm<true, true><<<nbm, 256, 0, stream>>>(x, xb, xa, W, b, out, N);
  } else if (ws_size >= nb_bf) {
    cvt_bf16<<<nbc, 256, 0, stream>>>(x, xb, total8);
    agg_k<true, false><<<nba, 256, 0, stream>>>(x, xb, row, colptr, out, xa, N);
    sage_mm<true, false><<<nbm, 256, 0, stream>>>(x, xb, xa, W, b, out, N);
  } else {
    agg_k<false, false><<<nba, 256, 0, stream>>>(x, xb, row, colptr, out, xa, N);
    sage_mm<false, false><<<nbm, 256, 0, stream>>>(x, xb, xa, W, b, out, N);
  }
}

// Round 9
// 79.446 us; speedup vs baseline: 1.1805x; 1.1805x over previous
//
#include <hip/hip_runtime.h>

typedef __bf16 bf16x8 __attribute__((ext_vector_type(8)));
typedef float  f32x4  __attribute__((ext_vector_type(4)));

__device__ __forceinline__ unsigned short f2bf(float f) {
  unsigned u = __float_as_uint(f);
  u = u + 0x7fffu + ((u >> 16) & 1u);   // RNE
  return (unsigned short)(u >> 16);
}
__device__ __forceinline__ float bf2f(unsigned short h) {
  return __uint_as_float(((unsigned)h) << 16);
}

// K0: convert x (f32) -> xb (bf16), 8 elems/thread
__global__ __launch_bounds__(256) void cvt_bf16(
    const float* __restrict__ x, unsigned short* __restrict__ xb, int total8) {
  int i = blockIdx.x * 256 + threadIdx.x;
  if (i >= total8) return;
  const float4* p = (const float4*)(x + (size_t)i * 8);
  float4 a = p[0], b = p[1];
  union { unsigned short u[8]; uint4 v; } r;
  r.u[0] = f2bf(a.x); r.u[1] = f2bf(a.y); r.u[2] = f2bf(a.z); r.u[3] = f2bf(a.w);
  r.u[4] = f2bf(b.x); r.u[5] = f2bf(b.y); r.u[6] = f2bf(b.z); r.u[7] = f2bf(b.w);
  ((uint4*)xb)[i] = r.v;
}

// K1 (bf16 path): mean aggregation, 1 node/wave. Paired-row dword gathers:
// lanes 0-31 read row A, lanes 32-63 read row B (4B = 2 features each) ->
// one vmem instruction covers 2 edges, exactly 2 cache lines, addresses from
// SGPRs (readlane) with no shfl in the address path. Batch of 16 edges =
// 8 instructions in flight; next batch's indices prefetched under them.
template <bool AGGBF>
__global__ __launch_bounds__(256) void agg_pair(
    const unsigned short* __restrict__ xb, const int* __restrict__ row,
    const int* __restrict__ colptr, float* __restrict__ aggf,
    unsigned short* __restrict__ aggb, int N) {
  int wid  = blockIdx.x * 4 + (threadIdx.x >> 6);
  int lane = threadIdx.x & 63;
  if (wid >= N) return;
  int s = __builtin_amdgcn_readfirstlane(colptr[wid]);
  int e = __builtin_amdgcn_readfirstlane(colptr[wid + 1]);
  int half = lane >> 5;          // 0: even edge of pair, 1: odd edge
  int fp   = lane & 31;          // feature pair (features 2fp, 2fp+1)
  float accE = 0.f, accO = 0.f;

  int t = s;
  if (t < e) {
    int li = lane & 15;
    int idxv = row[min(t + li, e - 1)];   // batch-16 indices, one trip
    for (;;) {
      int lim  = e - t;
      int nt   = t + 16;
      bool more = nt < e;
      int id0  = __builtin_amdgcn_readlane(idxv, 0);
      int id1  = __builtin_amdgcn_readlane(idxv, 1);
      int id2  = __builtin_amdgcn_readlane(idxv, 2);
      int id3  = __builtin_amdgcn_readlane(idxv, 3);
      int id4  = __builtin_amdgcn_readlane(idxv, 4);
      int id5  = __builtin_amdgcn_readlane(idxv, 5);
      int id6  = __builtin_amdgcn_readlane(idxv, 6);
      int id7  = __builtin_amdgcn_readlane(idxv, 7);
      int id8  = __builtin_amdgcn_readlane(idxv, 8);
      int id9  = __builtin_amdgcn_readlane(idxv, 9);
      int id10 = __builtin_amdgcn_readlane(idxv, 10);
      int id11 = __builtin_amdgcn_readlane(idxv, 11);
      int id12 = __builtin_amdgcn_readlane(idxv, 12);
      int id13 = __builtin_amdgcn_readlane(idxv, 13);
      int id14 = __builtin_amdgcn_readlane(idxv, 14);
      int id15 = __builtin_amdgcn_readlane(idxv, 15);
      if (more) idxv = row[min(nt + li, e - 1)];   // prefetch next indices
      unsigned g[8];
#define PGATH(Q, IA, IB)                                                     \
      {                                                                      \
        int sel = half ? (IB) : (IA);                                        \
        g[Q] = *(const unsigned*)(xb + (size_t)sel * 64 + fp * 2);           \
      }
      PGATH(0, id0,  id1)  PGATH(1, id2,  id3)
      PGATH(2, id4,  id5)  PGATH(3, id6,  id7)
      PGATH(4, id8,  id9)  PGATH(5, id10, id11)
      PGATH(6, id12, id13) PGATH(7, id14, id15)
#undef PGATH
      #pragma unroll
      for (int q = 0; q < 8; ++q) {
        float f0 = __uint_as_float(g[q] << 16);
        float f1 = __uint_as_float(g[q] & 0xffff0000u);
        if (2 * q + half < lim) { accE += f0; accO += f1; }
      }
      if (!more) break;
      t = nt;
    }
  }

  // fold odd/even edge halves (lane j <-> lane j+32)
  accE += __shfl_xor(accE, 32);
  accO += __shfl_xor(accO, 32);

  int deg = e - s;
  float sc = (deg > 0) ? (1.0f / (float)deg) : 0.0f;
  if (lane < 32) {   // 32 lanes x 4B = one coalesced 128B row
    if (AGGBF) {
      unsigned p = (unsigned)f2bf(accE * sc) | ((unsigned)f2bf(accO * sc) << 16);
      *(unsigned*)(aggb + (size_t)wid * 64 + fp * 2) = p;
    } else {
      float2 p; p.x = accE * sc; p.y = accO * sc;
      *(float2*)(aggf + (size_t)wid * 64 + fp * 2) = p;
    }
  }
}

// K1 fallback (no-ws): f32 gathers, round-6 structure.
__global__ __launch_bounds__(256) void agg_f32(
    const float* __restrict__ x, const int* __restrict__ row,
    const int* __restrict__ colptr, float* __restrict__ aggf, int N) {
  int wid  = blockIdx.x * 4 + (threadIdx.x >> 6);
  int lane = threadIdx.x & 63;
  if (wid >= N) return;
  int s = __builtin_amdgcn_readfirstlane(colptr[wid]);
  int e = __builtin_amdgcn_readfirstlane(colptr[wid + 1]);
  float acc = 0.0f;
  int t = s;
  if (t < e) {
    int li = lane & 15;
    int myidx = row[min(t + li, e - 1)];
    for (;;) {
      int lim  = e - t;
      int nt   = t + 16;
      bool more = nt < e;
      int idx[16];
      #pragma unroll
      for (int j = 0; j < 16; ++j) idx[j] = __builtin_amdgcn_readlane(myidx, j);
      if (more) myidx = row[min(nt + li, e - 1)];
      float g[16];
      #pragma unroll
      for (int j = 0; j < 16; ++j) g[j] = x[(size_t)idx[j] * 64 + lane];
      if (lim < 16) {
        #pragma unroll
        for (int j = 0; j < 16; ++j) if (j >= lim) g[j] = 0.0f;
      }
      acc += (((g[0] + g[1]) + (g[2] + g[3])) + ((g[4] + g[5]) + (g[6] + g[7])))
           + (((g[8] + g[9]) + (g[10] + g[11])) + ((g[12] + g[13]) + (g[14] + g[15])));
      if (!more) break;
      t = nt;
    }
  }
  int deg = e - s;
  aggf[(size_t)wid * 64 + lane] = (deg > 0) ? (acc / (float)deg) : 0.0f;
}

// K2: out[n] = b + [agg|x] @ W^T via bf16 MFMA 16x16x32.
template <bool BF, bool AGGBF>
__global__ __launch_bounds__(256) void sage_mm(
    const float* __restrict__ x, const unsigned short* __restrict__ xb,
    const unsigned short* __restrict__ aggb,
    const float* __restrict__ W, const float* __restrict__ b,
    float* __restrict__ out, int N) {
  __shared__ unsigned short ft[128][136];
  int tid = threadIdx.x;
  int l = tid & 63, w = tid >> 6;
  int colr = l & 15, kg = l >> 4;
  int n0 = blockIdx.x * 128;
  int rows = N - n0; if (rows > 128) rows = 128;

  bf16x8 bfrag[4][4];
  float bias[4];
  #pragma unroll
  for (int c = 0; c < 4; ++c) {
    bias[c] = b[c * 16 + colr];
    #pragma unroll
    for (int kq = 0; kq < 4; ++kq) {
      const float* wp = W + (size_t)(c * 16 + colr) * 128 + kq * 32 + kg * 8;
      float4 wa = *(const float4*)wp;
      float4 wb = *(const float4*)(wp + 4);
      union { unsigned short u[8]; bf16x8 v; } r;
      r.u[0] = f2bf(wa.x); r.u[1] = f2bf(wa.y); r.u[2] = f2bf(wa.z); r.u[3] = f2bf(wa.w);
      r.u[4] = f2bf(wb.x); r.u[5] = f2bf(wb.y); r.u[6] = f2bf(wb.z); r.u[7] = f2bf(wb.w);
      bfrag[c][kq] = r.v;
    }
  }

  const float* aggsrcf = out + (size_t)n0 * 64;
  #pragma unroll
  for (int it = 0; it < 4; ++it) {
    int flat = it * 2048 + tid * 8;
    int n = flat >> 6, k = flat & 63;
    { // agg half -> ft[n][0..63]
      uint4 v = make_uint4(0, 0, 0, 0);
      if (n < rows) {
        if (AGGBF) {
          v = *(const uint4*)(aggb + ((size_t)(n0 + n) * 64 + k));
        } else {
          const float4* p = (const float4*)(aggsrcf + (size_t)n * 64 + k);
          float4 a = p[0], bb = p[1];
          union { unsigned short u[8]; uint4 vv; } r;
          r.u[0] = f2bf(a.x);  r.u[1] = f2bf(a.y);  r.u[2] = f2bf(a.z);  r.u[3] = f2bf(a.w);
          r.u[4] = f2bf(bb.x); r.u[5] = f2bf(bb.y); r.u[6] = f2bf(bb.z); r.u[7] = f2bf(bb.w);
          v = r.vv;
        }
      }
      *(uint4*)&ft[n][k] = v;
    }
    { // x half -> ft[n][64..127]
      uint4 v = make_uint4(0, 0, 0, 0);
      if (n < rows) {
        if (BF) {
          v = *(const uint4*)(xb + ((size_t)(n0 + n) * 64 + k));
        } else {
          const float4* p = (const float4*)(x + (size_t)(n0 + n) * 64 + k);
          float4 a = p[0], bb = p[1];
          union { unsigned short u[8]; uint4 vv; } r;
          r.u[0] = f2bf(a.x);  r.u[1] = f2bf(a.y);  r.u[2] = f2bf(a.z);  r.u[3] = f2bf(a.w);
          r.u[4] = f2bf(bb.x); r.u[5] = f2bf(bb.y); r.u[6] = f2bf(bb.z); r.u[7] = f2bf(bb.w);
          v = r.vv;
        }
      }
      *(uint4*)&ft[n][64 + k] = v;
    }
  }
  __syncthreads();

  f32x4 acc[2][4];
  #pragma unroll
  for (int c = 0; c < 4; ++c) {
    acc[0][c] = (f32x4){bias[c], bias[c], bias[c], bias[c]};
    acc[1][c] = acc[0][c];
  }

  #pragma unroll
  for (int kq = 0; kq < 4; ++kq) {
    bf16x8 a0 = *(const bf16x8*)&ft[w * 32 + colr][kq * 32 + kg * 8];
    bf16x8 a1 = *(const bf16x8*)&ft[w * 32 + 16 + colr][kq * 32 + kg * 8];
    #pragma unroll
    for (int c = 0; c < 4; ++c) {
      acc[0][c] = __builtin_amdgcn_mfma_f32_16x16x32_bf16(a0, bfrag[c][kq], acc[0][c], 0, 0, 0);
      acc[1][c] = __builtin_amdgcn_mfma_f32_16x16x32_bf16(a1, bfrag[c][kq], acc[1][c], 0, 0, 0);
    }
  }

  #pragma unroll
  for (int m = 0; m < 2; ++m) {
    int nodeb = n0 + w * 32 + m * 16 + kg * 4;
    #pragma unroll
    for (int c = 0; c < 4; ++c) {
      #pragma unroll
      for (int r = 0; r < 4; ++r) {
        int node = nodeb + r;
        if (node < N) out[(size_t)node * 64 + c * 16 + colr] = acc[m][c][r];
      }
    }
  }
}

extern "C" void kernel_launch(void* const* d_in, const int* in_sizes, int n_in,
                              void* d_out, int out_size, void* d_ws, size_t ws_size,
                              hipStream_t stream) {
  const float* x      = (const float*)d_in[0];
  const int*   row    = (const int*)d_in[1];
  const int*   colptr = (const int*)d_in[2];
  const float* W      = (const float*)d_in[3];
  const float* b      = (const float*)d_in[4];
  float* out = (float*)d_out;

  int N = in_sizes[0] / 64;
  size_t nb_bf = (size_t)N * 64 * 2;   // bf16 x copy
  unsigned short* xb = (unsigned short*)d_ws;
  unsigned short* xa = (unsigned short*)((char*)d_ws + nb_bf);  // bf16 agg

  int total8 = N * 8;
  int nbc = (total8 + 255) / 256;
  int nba = (N + 3) / 4;
  int nbm = (N + 127) / 128;

  if (ws_size >= 2 * nb_bf) {
    cvt_bf16<<<nbc, 256, 0, stream>>>(x, xb, total8);
    agg_pair<true><<<nba, 256, 0, stream>>>(xb, row, colptr, out, xa, N);
    sage_mm<true, true><<<nbm, 256, 0, stream>>>(x, xb, xa, W, b, out, N);
  } else if (ws_size >= nb_bf) {
    cvt_bf16<<<nbc, 256, 0, stream>>>(x, xb, total8);
    agg_pair<false><<<nba, 256, 0, stream>>>(xb, row, colptr, out, xa, N);
    sage_mm<true, false><<<nbm, 256, 0, stream>>>(x, xb, xa, W, b, out, N);
  } else {
    agg_f32<<<nba, 256, 0, stream>>>(x, row, colptr, out, N);
    sage_mm<false, false><<<nbm, 256, 0, stream>>>(x, xb, xa, W, b, out, N);
  }
}

// Round 10
// 77.786 us; speedup vs baseline: 1.2056x; 1.0213x over previous
//
#include <hip/hip_runtime.h>

typedef __bf16 bf16x8 __attribute__((ext_vector_type(8)));
typedef float  f32x4  __attribute__((ext_vector_type(4)));

__device__ __forceinline__ unsigned short f2bf(float f) {
  unsigned u = __float_as_uint(f);
  u = u + 0x7fffu + ((u >> 16) & 1u);   // RNE
  return (unsigned short)(u >> 16);
}

// K0: convert x (f32) -> xb (bf16), 8 elems/thread
__global__ __launch_bounds__(256) void cvt_bf16(
    const float* __restrict__ x, unsigned short* __restrict__ xb, int total8) {
  int i = blockIdx.x * 256 + threadIdx.x;
  if (i >= total8) return;
  const float4* p = (const float4*)(x + (size_t)i * 8);
  float4 a = p[0], b = p[1];
  union { unsigned short u[8]; uint4 v; } r;
  r.u[0] = f2bf(a.x); r.u[1] = f2bf(a.y); r.u[2] = f2bf(a.z); r.u[3] = f2bf(a.w);
  r.u[4] = f2bf(b.x); r.u[5] = f2bf(b.y); r.u[6] = f2bf(b.z); r.u[7] = f2bf(b.w);
  ((uint4*)xb)[i] = r.v;
}

// K1: mean aggregation, 1 node/wave, paired-row dword gathers with minimal
// VALU. Pair of edges (A,B): SALU computes base=min(A,B)*128 and df=|A-B|*128;
// lanes 0-31 read base+fp4, lanes 32-63 read base+df+fp4 (one cndmask + add).
// A sum is order-independent, so which half gets which edge doesn't matter.
// Full batches (16 edges) carry zero predication; tail uses uniform branches.
template <bool AGGBF>
__global__ __launch_bounds__(256) void agg_pair(
    const unsigned short* __restrict__ xb, const int* __restrict__ row,
    const int* __restrict__ colptr, float* __restrict__ aggf,
    unsigned short* __restrict__ aggb, int N) {
  int wid  = blockIdx.x * 4 + (threadIdx.x >> 6);
  int lane = threadIdx.x & 63;
  if (wid >= N) return;
  int s = __builtin_amdgcn_readfirstlane(colptr[wid]);
  int e = __builtin_amdgcn_readfirstlane(colptr[wid + 1]);
  bool hi = lane >= 32;
  int  fp4 = (lane & 31) * 4;     // byte offset: features 2fp, 2fp+1
  int  li  = lane & 15;
  float acc0 = 0.f, acc1 = 0.f;

  int deg   = e - s;
  int nfull = deg & ~15;

  // ---- main: full batches of 16 edges (8 pair-gathers), no predication ----
  if (nfull) {
    int t = s;
    int idxv = row[t + li];                  // 16 indices, one trip
    for (;;) {
      int nt = t + 16;
      bool more = nt < s + nfull;
      int id[16];
      #pragma unroll
      for (int j = 0; j < 16; ++j) id[j] = __builtin_amdgcn_readlane(idxv, j);
      if (more) idxv = row[nt + li];         // prefetch under gathers
      unsigned g[8];
      #pragma unroll
      for (int q = 0; q < 8; ++q) {
        int a = id[2 * q], b = id[2 * q + 1];
        int mn = min(a, b);
        int df = (max(a, b) - mn) * 128;     // SALU
        const char* base = (const char*)xb + (size_t)mn * 128;
        int voff = (hi ? df : 0) + fp4;      // cndmask + add
        g[q] = *(const unsigned*)(base + voff);
      }
      #pragma unroll
      for (int q = 0; q < 8; ++q) {
        acc0 += __uint_as_float(g[q] << 16);
        acc1 += __uint_as_float(g[q] & 0xffff0000u);
      }
      if (!more) break;
      t = nt;
    }
  }

  // ---- tail: rem in 1..15 edges, uniform pair count ----
  int t = s + nfull;
  int rem = e - t;
  if (rem > 0) {
    int idxv = row[min(t + li, e - 1)];
    int id[16];
    #pragma unroll
    for (int j = 0; j < 16; ++j) id[j] = __builtin_amdgcn_readlane(idxv, j);
    int npairs = (rem + 1) >> 1;
    bool odd = (rem & 1) != 0;
    unsigned g[8];
    #pragma unroll
    for (int q = 0; q < 8; ++q) {
      if (q < npairs) {                      // uniform branch
        int a = id[2 * q], b = id[2 * q + 1];
        int mn = min(a, b);
        int df = (max(a, b) - mn) * 128;
        const char* base = (const char*)xb + (size_t)mn * 128;
        int voff = (hi ? df : 0) + fp4;
        g[q] = *(const unsigned*)(base + voff);
      }
    }
    #pragma unroll
    for (int q = 0; q < 8; ++q) {
      if (q < npairs) {
        unsigned v = g[q];
        if (odd && q == npairs - 1)          // lone edge: count once
          v = hi ? 0u : v;
        acc0 += __uint_as_float(v << 16);
        acc1 += __uint_as_float(v & 0xffff0000u);
      }
    }
  }

  // fold the two edge-halves (lane j <-> j+32)
  acc0 += __shfl_xor(acc0, 32);
  acc1 += __shfl_xor(acc1, 32);

  float sc = (deg > 0) ? (1.0f / (float)deg) : 0.0f;
  if (lane < 32) {                           // 32 lanes x 4B = 128B row
    if (AGGBF) {
      unsigned p = (unsigned)f2bf(acc0 * sc) | ((unsigned)f2bf(acc1 * sc) << 16);
      *(unsigned*)(aggb + (size_t)wid * 64 + (lane & 31) * 2) = p;
    } else {
      float2 p; p.x = acc0 * sc; p.y = acc1 * sc;
      *(float2*)(aggf + (size_t)wid * 64 + (lane & 31) * 2) = p;
    }
  }
}

// K1 fallback (no-ws): f32 gathers, round-6 structure.
__global__ __launch_bounds__(256) void agg_f32(
    const float* __restrict__ x, const int* __restrict__ row,
    const int* __restrict__ colptr, float* __restrict__ aggf, int N) {
  int wid  = blockIdx.x * 4 + (threadIdx.x >> 6);
  int lane = threadIdx.x & 63;
  if (wid >= N) return;
  int s = __builtin_amdgcn_readfirstlane(colptr[wid]);
  int e = __builtin_amdgcn_readfirstlane(colptr[wid + 1]);
  float acc = 0.0f;
  int t = s;
  if (t < e) {
    int li = lane & 15;
    int myidx = row[min(t + li, e - 1)];
    for (;;) {
      int lim  = e - t;
      int nt   = t + 16;
      bool more = nt < e;
      int idx[16];
      #pragma unroll
      for (int j = 0; j < 16; ++j) idx[j] = __builtin_amdgcn_readlane(myidx, j);
      if (more) myidx = row[min(nt + li, e - 1)];
      float g[16];
      #pragma unroll
      for (int j = 0; j < 16; ++j) g[j] = x[(size_t)idx[j] * 64 + lane];
      if (lim < 16) {
        #pragma unroll
        for (int j = 0; j < 16; ++j) if (j >= lim) g[j] = 0.0f;
      }
      acc += (((g[0] + g[1]) + (g[2] + g[3])) + ((g[4] + g[5]) + (g[6] + g[7])))
           + (((g[8] + g[9]) + (g[10] + g[11])) + ((g[12] + g[13]) + (g[14] + g[15])));
      if (!more) break;
      t = nt;
    }
  }
  int deg = e - s;
  aggf[(size_t)wid * 64 + lane] = (deg > 0) ? (acc / (float)deg) : 0.0f;
}

// K2: out[n] = b + [agg|x] @ W^T via bf16 MFMA 16x16x32.
template <bool BF, bool AGGBF>
__global__ __launch_bounds__(256) void sage_mm(
    const float* __restrict__ x, const unsigned short* __restrict__ xb,
    const unsigned short* __restrict__ aggb,
    const float* __restrict__ W, const float* __restrict__ b,
    float* __restrict__ out, int N) {
  __shared__ unsigned short ft[128][136];
  int tid = threadIdx.x;
  int l = tid & 63, w = tid >> 6;
  int colr = l & 15, kg = l >> 4;
  int n0 = blockIdx.x * 128;
  int rows = N - n0; if (rows > 128) rows = 128;

  bf16x8 bfrag[4][4];
  float bias[4];
  #pragma unroll
  for (int c = 0; c < 4; ++c) {
    bias[c] = b[c * 16 + colr];
    #pragma unroll
    for (int kq = 0; kq < 4; ++kq) {
      const float* wp = W + (size_t)(c * 16 + colr) * 128 + kq * 32 + kg * 8;
      float4 wa = *(const float4*)wp;
      float4 wb = *(const float4*)(wp + 4);
      union { unsigned short u[8]; bf16x8 v; } r;
      r.u[0] = f2bf(wa.x); r.u[1] = f2bf(wa.y); r.u[2] = f2bf(wa.z); r.u[3] = f2bf(wa.w);
      r.u[4] = f2bf(wb.x); r.u[5] = f2bf(wb.y); r.u[6] = f2bf(wb.z); r.u[7] = f2bf(wb.w);
      bfrag[c][kq] = r.v;
    }
  }

  const float* aggsrcf = out + (size_t)n0 * 64;
  #pragma unroll
  for (int it = 0; it < 4; ++it) {
    int flat = it * 2048 + tid * 8;
    int n = flat >> 6, k = flat & 63;
    { // agg half -> ft[n][0..63]
      uint4 v = make_uint4(0, 0, 0, 0);
      if (n < rows) {
        if (AGGBF) {
          v = *(const uint4*)(aggb + ((size_t)(n0 + n) * 64 + k));
        } else {
          const float4* p = (const float4*)(aggsrcf + (size_t)n * 64 + k);
          float4 a = p[0], bb = p[1];
          union { unsigned short u[8]; uint4 vv; } r;
          r.u[0] = f2bf(a.x);  r.u[1] = f2bf(a.y);  r.u[2] = f2bf(a.z);  r.u[3] = f2bf(a.w);
          r.u[4] = f2bf(bb.x); r.u[5] = f2bf(bb.y); r.u[6] = f2bf(bb.z); r.u[7] = f2bf(bb.w);
          v = r.vv;
        }
      }
      *(uint4*)&ft[n][k] = v;
    }
    { // x half -> ft[n][64..127]
      uint4 v = make_uint4(0, 0, 0, 0);
      if (n < rows) {
        if (BF) {
          v = *(const uint4*)(xb + ((size_t)(n0 + n) * 64 + k));
        } else {
          const float4* p = (const float4*)(x + (size_t)(n0 + n) * 64 + k);
          float4 a = p[0], bb = p[1];
          union { unsigned short u[8]; uint4 vv; } r;
          r.u[0] = f2bf(a.x);  r.u[1] = f2bf(a.y);  r.u[2] = f2bf(a.z);  r.u[3] = f2bf(a.w);
          r.u[4] = f2bf(bb.x); r.u[5] = f2bf(bb.y); r.u[6] = f2bf(bb.z); r.u[7] = f2bf(bb.w);
          v = r.vv;
        }
      }
      *(uint4*)&ft[n][64 + k] = v;
    }
  }
  __syncthreads();

  f32x4 acc[2][4];
  #pragma unroll
  for (int c = 0; c < 4; ++c) {
    acc[0][c] = (f32x4){bias[c], bias[c], bias[c], bias[c]};
    acc[1][c] = acc[0][c];
  }

  #pragma unroll
  for (int kq = 0; kq < 4; ++kq) {
    bf16x8 a0 = *(const bf16x8*)&ft[w * 32 + colr][kq * 32 + kg * 8];
    bf16x8 a1 = *(const bf16x8*)&ft[w * 32 + 16 + colr][kq * 32 + kg * 8];
    #pragma unroll
    for (int c = 0; c < 4; ++c) {
      acc[0][c] = __builtin_amdgcn_mfma_f32_16x16x32_bf16(a0, bfrag[c][kq], acc[0][c], 0, 0, 0);
      acc[1][c] = __builtin_amdgcn_mfma_f32_16x16x32_bf16(a1, bfrag[c][kq], acc[1][c], 0, 0, 0);
    }
  }

  #pragma unroll
  for (int m = 0; m < 2; ++m) {
    int nodeb = n0 + w * 32 + m * 16 + kg * 4;
    #pragma unroll
    for (int c = 0; c < 4; ++c) {
      #pragma unroll
      for (int r = 0; r < 4; ++r) {
        int node = nodeb + r;
        if (node < N) out[(size_t)node * 64 + c * 16 + colr] = acc[m][c][r];
      }
    }
  }
}

extern "C" void kernel_launch(void* const* d_in, const int* in_sizes, int n_in,
                              void* d_out, int out_size, void* d_ws, size_t ws_size,
                              hipStream_t stream) {
  const float* x      = (const float*)d_in[0];
  const int*   row    = (const int*)d_in[1];
  const int*   colptr = (const int*)d_in[2];
  const float* W      = (const float*)d_in[3];
  const float* b      = (const float*)d_in[4];
  float* out = (float*)d_out;

  int N = in_sizes[0] / 64;
  size_t nb_bf = (size_t)N * 64 * 2;   // bf16 x copy
  unsigned short* xb = (unsigned short*)d_ws;
  unsigned short* xa = (unsigned short*)((char*)d_ws + nb_bf);  // bf16 agg

  int total8 = N * 8;
  int nbc = (total8 + 255) / 256;
  int nba = (N + 3) / 4;
  int nbm = (N + 127) / 128;

  if (ws_size >= 2 * nb_bf) {
    cvt_bf16<<<nbc, 256, 0, stream>>>(x, xb, total8);
    agg_pair<true><<<nba, 256, 0, stream>>>(xb, row, colptr, out, xa, N);
    sage_mm<true, true><<<nbm, 256, 0, stream>>>(x, xb, xa, W, b, out, N);
  } else if (ws_size >= nb_bf) {
    cvt_bf16<<<nbc, 256, 0, stream>>>(x, xb, total8);
    agg_pair<false><<<nba, 256, 0, stream>>>(xb, row, colptr, out, xa, N);
    sage_mm<true, false><<<nbm, 256, 0, stream>>>(x, xb, xa, W, b, out, N);
  } else {
    agg_f32<<<nba, 256, 0, stream>>>(x, row, colptr, out, N);
    sage_mm<false, false><<<nbm, 256, 0, stream>>>(x, xb, xa, W, b, out, N);
  }
}